// Round 5
// baseline (907.368 us; speedup 1.0000x reference)
//
#include <hip/hip_runtime.h>
#include <hip/hip_bf16.h>
#include <math.h>

#define N_TOKENS 16
#define TOK_DIM 64
#define NODE_DIM 64
#define HID 128
#define FC 128
#define NUM_GRAPHS 1024
#define SCAN_B 256

// ---------------- embed + token-mean + Wp projection -> node64[N,64] ----------------
// 256 threads = 4 nodes/block, one wave per node
__global__ void embed_project_kernel(const int* __restrict__ tok,
                                     const float* __restrict__ emb,
                                     const float* __restrict__ Wp,
                                     const float* __restrict__ bp,
                                     float* __restrict__ node64, int N) {
    __shared__ float smean[4][64];
    int t = threadIdx.x;
    int w = t >> 6, j = t & 63;
    int i = blockIdx.x * 4 + w;
    if (i < N) {
        int vt = tok[i * N_TOKENS + (j & 15)];  // lanes 0..15 hold the 16 token ids
        float s = 0.f;
#pragma unroll
        for (int tt = 0; tt < N_TOKENS; tt++) {
            int v = __shfl(vt, tt, 64);
            s += emb[v * TOK_DIM + j];
        }
        smean[w][j] = s * (1.0f / (float)N_TOKENS);
    }
    __syncthreads();
    if (i < N) {
        float acc = bp[j];
#pragma unroll
        for (int k = 0; k < TOK_DIM; k++) acc += smean[w][k] * Wp[k * NODE_DIM + j];
        node64[(size_t)i * 64 + j] = acc;
    }
}

// ---------------- degree histogram ----------------
__global__ void hist_kernel(const int* __restrict__ dst, int* __restrict__ hist, int E) {
    int e = blockIdx.x * blockDim.x + threadIdx.x;
    if (e < E) atomicAdd(&hist[dst[e]], 1);
}

// ---------------- scan local + dis + cursor reset (fused) ----------------
__global__ void scan_local_kernel(int* __restrict__ hist, int* __restrict__ row_start,
                                  int* __restrict__ bsums, float* __restrict__ dis, int N) {
    __shared__ int s[SCAN_B];
    int tid = threadIdx.x;
    int i = blockIdx.x * SCAN_B + tid;
    int v = (i < N) ? hist[i] : 0;
    s[tid] = v;
    __syncthreads();
    for (int off = 1; off < SCAN_B; off <<= 1) {
        int add = (tid >= off) ? s[tid - off] : 0;
        __syncthreads();
        s[tid] += add;
        __syncthreads();
    }
    if (i < N) {
        row_start[i] = s[tid] - v;                 // exclusive (block-local)
        dis[i] = rsqrtf(1.0f + (float)v);          // +1 self loop
        hist[i] = 0;                               // reset: hist doubles as cursor
    }
    if (tid == SCAN_B - 1) bsums[blockIdx.x] = s[SCAN_B - 1];
}

// single block, 512 threads; nb <= 512
__global__ void scan_bsums_kernel(int* __restrict__ bsums, int nb) {
    __shared__ int s[512];
    int tid = threadIdx.x;
    int v = (tid < nb) ? bsums[tid] : 0;
    s[tid] = v;
    __syncthreads();
    for (int off = 1; off < 512; off <<= 1) {
        int add = (tid >= off) ? s[tid - off] : 0;
        __syncthreads();
        s[tid] += add;
        __syncthreads();
    }
    if (tid < nb) bsums[tid] = s[tid] - v;  // exclusive
    if (tid == 511) bsums[nb] = s[511];     // total
}

__global__ void scan_add_kernel(int* __restrict__ row_start, const int* __restrict__ bsums,
                                int N, int nb) {
    int i = blockIdx.x * blockDim.x + threadIdx.x;
    if (i < N) row_start[i] += bsums[i >> 8];
    else if (i == N) row_start[N] = bsums[nb];
}

// ---------------- CSR fill, packed (src, weight) int2 ----------------
__global__ void fill_csr_kernel(const int* __restrict__ src, const int* __restrict__ dst,
                                const int* __restrict__ row_start, int* __restrict__ cursor,
                                const float* __restrict__ dis,
                                int2* __restrict__ csr, int E) {
    int e = blockIdx.x * blockDim.x + threadIdx.x;
    if (e < E) {
        int d = dst[e];
        int s = src[e];
        int pos = atomicAdd(&cursor[d], 1);
        int o = row_start[d] + pos;
        csr[o] = make_int2(s, __float_as_int(dis[s] * dis[d]));
    }
}

// ---------------- layer 1 fused: agg64 (shfl-staged, MLP=8) + W1 + b1 + ReLU + W2 -> y ----------------
// 256 threads = 4 nodes/block, one wave per node (lane j = feature 0..63)
__global__ void gcn_layer1_kernel(const float* __restrict__ node64,
                                  const int* __restrict__ row_start,
                                  const int2* __restrict__ csr,
                                  const float* __restrict__ dis,
                                  const float* __restrict__ W1,
                                  const float* __restrict__ b1,
                                  const float* __restrict__ W2,
                                  float* __restrict__ y, int N) {
    __shared__ float sagg[4][64];
    __shared__ float sx1[4][128];
    int t = threadIdx.x;
    int w = t >> 6, j = t & 63;
    int node = blockIdx.x * 4 + w;
    if (node < N) {
        int beg = row_start[node];
        int end = row_start[node + 1];
        float d = dis[node];
        float acc = node64[(size_t)node * 64 + j] * d * d;
        for (int chunk = beg; chunk < end; chunk += 64) {
            int mm = end - chunk; if (mm > 64) mm = 64;
            int2 e = (j < mm) ? csr[chunk + j] : make_int2(0, 0);  // pad: row0 * 0.0
            int rounds = (mm + 7) >> 3;
            for (int r = 0; r < rounds; r++) {
                int b8 = r << 3;
                int si[8]; float wv[8], v[8];
#pragma unroll
                for (int u = 0; u < 8; u++) {
                    si[u] = __shfl(e.x, b8 + u, 64);
                    wv[u] = __int_as_float(__shfl(e.y, b8 + u, 64));
                }
#pragma unroll
                for (int u = 0; u < 8; u++) v[u] = node64[(size_t)si[u] * 64 + j];
#pragma unroll
                for (int u = 0; u < 8; u++) acc += v[u] * wv[u];
            }
        }
        sagg[w][j] = acc;
    }
    __syncthreads();
    if (node < N) {
        float o0 = b1[j], o1 = b1[j + 64];
#pragma unroll
        for (int k = 0; k < 64; k++) {
            float a = sagg[w][k];
            o0 += a * W1[k * 128 + j];
            o1 += a * W1[k * 128 + j + 64];
        }
        sx1[w][j] = fmaxf(o0, 0.f);
        sx1[w][j + 64] = fmaxf(o1, 0.f);
    }
    __syncthreads();
    if (node < N) {
        const float2* W2v = (const float2*)W2;  // row k, col pair j => W2v[k*64+j]
        float2 yy = make_float2(0.f, 0.f);
#pragma unroll 8
        for (int k = 0; k < 128; k++) {
            float a = sx1[w][k];
            float2 wk = W2v[k * 64 + j];
            yy.x += a * wk.x;
            yy.y += a * wk.y;
        }
        ((float2*)y)[(size_t)node * 64 + j] = yy;  // y = relu(aggW1+b1) @ W2 (no bias/relu yet)
    }
}

// ---------------- layer 2: pure 128-dim gather (float2, MLP=8) + b2 + ReLU ----------------
// 256 threads = 4 nodes/block, one wave per node, lane j = dims (2j, 2j+1)
__global__ void gcn_layer2_kernel(const float* __restrict__ y,
                                  const int* __restrict__ row_start,
                                  const int2* __restrict__ csr,
                                  const float* __restrict__ dis,
                                  const float* __restrict__ b2,
                                  float* __restrict__ outx, int N) {
    int t = threadIdx.x;
    int w = t >> 6, j = t & 63;
    int node = blockIdx.x * 4 + w;
    if (node >= N) return;
    const float2* y2 = (const float2*)y;
    int beg = row_start[node];
    int end = row_start[node + 1];
    float d = dis[node];
    float2 self = y2[(size_t)node * 64 + j];
    float2 acc = make_float2(self.x * d * d, self.y * d * d);
    for (int chunk = beg; chunk < end; chunk += 64) {
        int mm = end - chunk; if (mm > 64) mm = 64;
        int2 e = (j < mm) ? csr[chunk + j] : make_int2(0, 0);
        int rounds = (mm + 7) >> 3;
        for (int r = 0; r < rounds; r++) {
            int b8 = r << 3;
            int si[8]; float wv[8]; float2 v[8];
#pragma unroll
            for (int u = 0; u < 8; u++) {
                si[u] = __shfl(e.x, b8 + u, 64);
                wv[u] = __int_as_float(__shfl(e.y, b8 + u, 64));
            }
#pragma unroll
            for (int u = 0; u < 8; u++) v[u] = y2[(size_t)si[u] * 64 + j];
#pragma unroll
            for (int u = 0; u < 8; u++) { acc.x += v[u].x * wv[u]; acc.y += v[u].y * wv[u]; }
        }
    }
    const float2* b22 = (const float2*)b2;
    float2 bb = b22[j];
    float2 o = make_float2(fmaxf(acc.x + bb.x, 0.f), fmaxf(acc.y + bb.y, 0.f));
    ((float2*)outx)[(size_t)node * 64 + j] = o;
}

// ---------------- atomic-free global mean pool (batch sorted), float2 ----------------
__device__ __forceinline__ int lower_bound_i(const int* __restrict__ a, int n, int val) {
    int lo = 0, hi = n;
    while (lo < hi) {
        int mid = (lo + hi) >> 1;
        if (a[mid] < val) lo = mid + 1; else hi = mid;
    }
    return lo;
}

// 256 threads = 4 graphs/block, one wave per graph
__global__ void pool_mean_kernel(const float* __restrict__ x,
                                 const int* __restrict__ batch,
                                 float* __restrict__ g, int N) {
    int t = threadIdx.x;
    int w = t >> 6, j = t & 63;
    int gr = blockIdx.x * 4 + w;
    if (gr >= NUM_GRAPHS) return;
    int beg = lower_bound_i(batch, N, gr);
    int end = lower_bound_i(batch, N, gr + 1);
    const float2* x2 = (const float2*)x;
    float2 acc = make_float2(0.f, 0.f);
    int i = beg;
    for (; i + 4 <= end; i += 4) {
        float2 a0 = x2[(size_t)i * 64 + j];
        float2 a1 = x2[(size_t)(i + 1) * 64 + j];
        float2 a2 = x2[(size_t)(i + 2) * 64 + j];
        float2 a3 = x2[(size_t)(i + 3) * 64 + j];
        acc.x += a0.x + a1.x + a2.x + a3.x;
        acc.y += a0.y + a1.y + a2.y + a3.y;
    }
    for (; i < end; i++) {
        float2 a = x2[(size_t)i * 64 + j];
        acc.x += a.x; acc.y += a.y;
    }
    float inv = 1.0f / fmaxf((float)(end - beg), 1.0f);
    ((float2*)g)[(size_t)gr * 64 + j] = make_float2(acc.x * inv, acc.y * inv);
}

// ---------------- head ----------------
__global__ void head_kernel(const float* __restrict__ g,
                            const float* __restrict__ Wfc,
                            const float* __restrict__ bfc,
                            const float* __restrict__ Wout,
                            const float* __restrict__ bout,
                            float* __restrict__ out) {
    int gr = blockIdx.x;
    int j = threadIdx.x;  // 0..127
    __shared__ float sg[128];
    __shared__ float sred[128];
    sg[j] = g[gr * 128 + j];
    __syncthreads();
    float acc = bfc[j];
#pragma unroll
    for (int k = 0; k < 128; k++) acc += sg[k] * Wfc[k * 128 + j];
    float f = fmaxf(acc, 0.f);
    sred[j] = f * Wout[j];
    __syncthreads();
    if (j < 64) sred[j] += sred[j + 64];
    __syncthreads();
    if (j < 64) {
        float v = sred[j];
#pragma unroll
        for (int off = 32; off > 0; off >>= 1) v += __shfl_down(v, off);
        if (j == 0) {
            float logit = v + bout[0];
            out[gr] = 1.0f / (1.0f + expf(-logit));
            out[NUM_GRAPHS + gr] = logit;
        }
    }
}

extern "C" void kernel_launch(void* const* d_in, const int* in_sizes, int n_in,
                              void* d_out, int out_size, void* d_ws, size_t ws_size,
                              hipStream_t stream) {
    const int* tok   = (const int*)d_in[0];
    const int* eidx  = (const int*)d_in[1];
    const int* batch = (const int*)d_in[2];
    const float* emb = (const float*)d_in[3];
    const float* Wp  = (const float*)d_in[4];
    const float* bp  = (const float*)d_in[5];
    const float* W1  = (const float*)d_in[6];
    const float* b1  = (const float*)d_in[7];
    const float* W2  = (const float*)d_in[8];
    const float* b2  = (const float*)d_in[9];
    const float* Wfc = (const float*)d_in[10];
    const float* bfc = (const float*)d_in[11];
    const float* Wout= (const float*)d_in[12];
    const float* bout= (const float*)d_in[13];
    float* out = (float*)d_out;

    const int N = in_sizes[2];
    const int E = in_sizes[1] / 2;
    const int* src = eidx;
    const int* dst = eidx + E;
    const int nb_scan = (N + SCAN_B - 1) / SCAN_B;
    const int Np = (N + 3) & ~3;  // even-sized segments => 8B alignment everywhere

    // workspace layout (floats)
    float* ws = (float*)d_ws;
    float* dis    = ws;                            // Np
    float* node64 = dis + Np;                      // Np*64
    float* ybuf   = node64 + (size_t)Np * 64;      // Np*128  (x1 @ W2)
    float* xfin   = ybuf + (size_t)Np * 128;       // Np*128  (layer-2 output)
    float* g      = xfin + (size_t)Np * 128;       // 1024*128
    int* row_start = (int*)(g + NUM_GRAPHS * 128); // Np+4
    int* hist      = row_start + Np + 4;           // Np (doubles as cursor)
    int* bsums     = hist + Np;                    // 1026
    int2* csr      = (int2*)(bsums + 1026);        // E int2

    // --- degree histogram ---
    hipMemsetAsync(hist, 0, N * sizeof(int), stream);
    hist_kernel<<<(E + 255) / 256, 256, 0, stream>>>(dst, hist, E);

    // --- scan (fused: dis + cursor reset) ---
    scan_local_kernel<<<nb_scan, SCAN_B, 0, stream>>>(hist, row_start, bsums, dis, N);
    scan_bsums_kernel<<<1, 512, 0, stream>>>(bsums, nb_scan);
    scan_add_kernel<<<(N + 1 + 255) / 256, 256, 0, stream>>>(row_start, bsums, N, nb_scan);

    // --- CSR fill (hist is the zeroed cursor) ---
    fill_csr_kernel<<<(E + 255) / 256, 256, 0, stream>>>(src, dst, row_start, hist, dis,
                                                         csr, E);

    // --- embed + mean + Wp -> node64 ---
    embed_project_kernel<<<(N + 3) / 4, 256, 0, stream>>>(tok, emb, Wp, bp, node64, N);

    // --- layer 1: agg64 + W1 + b1 + ReLU + W2 -> y ---
    gcn_layer1_kernel<<<(N + 3) / 4, 256, 0, stream>>>(node64, row_start, csr, dis,
                                                       W1, b1, W2, ybuf, N);

    // --- layer 2: gather y + b2 + ReLU -> xfin ---
    gcn_layer2_kernel<<<(N + 3) / 4, 256, 0, stream>>>(ybuf, row_start, csr, dis, b2,
                                                       xfin, N);

    // --- global mean pool + head ---
    pool_mean_kernel<<<(NUM_GRAPHS + 3) / 4, 256, 0, stream>>>(xfin, batch, g, N);
    head_kernel<<<NUM_GRAPHS, 128, 0, stream>>>(g, Wfc, bfc, Wout, bout, out);
}